// Round 8
// baseline (382.065 us; speedup 1.0000x reference)
//
#include <hip/hip_runtime.h>
#include <hip/hip_bf16.h>

typedef __bf16 bf16x8 __attribute__((ext_vector_type(8)));
typedef float f32x4 __attribute__((ext_vector_type(4)));

static constexpr int Tn = 8192;
static constexpr int Cn = 1024;

#define DEVI __device__ __forceinline__

DEVI float bf2f(ushort u) { union { uint i; float f; } c; c.i = ((uint)u) << 16; return c.f; }
DEVI ushort f2bf(float f) {
  uint x = __builtin_bit_cast(uint, f);
  x += 0x7fffu + ((x >> 16) & 1u);   // RNE
  return (ushort)(x >> 16);
}

typedef const __attribute__((address_space(1))) void glb_v;
typedef __attribute__((address_space(3))) void lds_v;

#define BAR()   __builtin_amdgcn_s_barrier()
#define SCH0()  __builtin_amdgcn_sched_barrier(0)
#define PRIO1() __builtin_amdgcn_s_setprio(1)
#define PRIO0() __builtin_amdgcn_s_setprio(0)

// ---------------------------------------------------------------- cast + concat + l-zero
__global__ __launch_bounds__(256) void cast_all(
    const float* __restrict__ x, const float* __restrict__ wq, const float* __restrict__ wk,
    const float* __restrict__ wv, const float* __restrict__ wp,
    const float* __restrict__ bq, const float* __restrict__ bk, const float* __restrict__ bv,
    ushort* __restrict__ xb, ushort* __restrict__ wqkv, ushort* __restrict__ wpb,
    float* __restrict__ bqkv, float* __restrict__ lsum)
{
  const long long NX = (long long)Tn * Cn;
  const long long NW = (long long)Cn * Cn;      // 2^20
  if (blockIdx.x == 12291) {   // zero the softmax-denominator accumulator
    float4 z; z.x = z.y = z.z = z.w = 0.f;
#pragma unroll
    for (int j = 0; j < 8; ++j) ((float4*)lsum)[threadIdx.x * 8 + j] = z;
    return;
  }
  if (blockIdx.x >= 12288) {   // bias concat (3 blocks)
    int id = ((blockIdx.x - 12288) * 256 + threadIdx.x) * 4;
#pragma unroll
    for (int e = 0; e < 4; ++e) {
      int j = id + e;
      if (j < 3 * Cn) bqkv[j] = j < Cn ? bq[j] : (j < 2 * Cn ? bk[j - Cn] : bv[j - 2 * Cn]);
    }
    return;
  }
  long long i = ((long long)blockIdx.x * 256 + threadIdx.x) * 4;
  const float* src; ushort* dst; long long off;
  if (i < NX) { src = x; dst = xb; off = i; }
  else {
    long long r = i - NX; int seg = (int)(r >> 20); off = r & (NW - 1);
    if (seg < 3) { src = seg == 0 ? wq : seg == 1 ? wk : wv; dst = wqkv + (size_t)seg * NW; }
    else         { src = wp; dst = wpb; }
  }
  float4 v = *reinterpret_cast<const float4*>(src + off);
  ushort4 o; o.x = f2bf(v.x); o.y = f2bf(v.y); o.z = f2bf(v.z); o.w = f2bf(v.w);
  *reinterpret_cast<ushort4*>(dst + off) = o;
}

// ---------------------------------------------------------------- register-pipelined GEMM, depth-3
// C[M,N] = A[M,K] @ Bt[N,K]^T. 128x128 tile, 4 waves (2x2, per-wave 64x64),
// BK=64, TRIPLE-buffered 96KB LDS: 2 tiles always in flight ahead.
//  iter t (buf b): issue slice1(t) ds_reads -> lgkmcnt(8) -> MFMA slice0 ->
//  lgkmcnt(0) -> BAR [buf b free] -> stage(t+3 -> b) -> vmcnt(16) [t+1 landed,
//  t+2/t+3 in flight] -> BAR -> issue slice0(t+1) reads -> MFMA slice1.
// vmcnt never drains below 16 in-loop; every MFMA sits behind a counted wait
// + sched_barrier (rule #18).
// QKT: dispatch-transposed (by=blockIdx.x -> consecutive blocks share the K
//      panel, QKV-style locality); causal skip; epilogue exp + atomic row-sums.
// PVM: by reversed (longest K first), causal K-limit, epilogue * 1/lsum[row].
template<bool OUT_BF16, bool HAS_BIAS, bool QKT, bool PVM, bool SPLIT3>
__global__ __launch_bounds__(256, 2)
void gemm_rp(const ushort* __restrict__ A, const ushort* __restrict__ Bt,
             const float* __restrict__ bias, void* __restrict__ outp,
             float* __restrict__ lsum,
             int K, int lda, int ldb, int ldc, float scale)
{
  __shared__ __align__(16) ushort sm[49152];   // 3 bufs x (A 8192 + B 8192) = 96 KB

  const int tid = threadIdx.x, lane = tid & 63, wid = tid >> 6;
  const int wm = wid >> 1, wn = wid & 1;
  const int ln15 = lane & 15, lsec = lane >> 4;

  int bx, by;
  if (QKT) {                       // transposed dispatch: x sweeps rows (Q),
    by = blockIdx.x;               // y picks the shared K panel
    bx = blockIdx.y;
    if (by < bx) return;
  } else {
    bx = blockIdx.x;
    by = PVM ? ((int)gridDim.y - 1 - (int)blockIdx.y) : (int)blockIdx.y;
  }
  const int rowA0 = by * 128, col0 = bx * 128;
  int NT = K >> 6;
  if (PVM) { int kl = (by + 1) * 128; if (kl < K) NT = kl >> 6; }

  const uint smb = (uint)(uintptr_t)&sm[0];

  // staging: 8 x global_load_lds(16B) per tile into elem-base eb
  auto stage = [&](int t, uint eb) {
    const int tt = t < NT ? t : NT - 1;
    const size_t k0 = (size_t)(tt << 6);
#pragma unroll
    for (int i = 0; i < 4; ++i) {
      int s = tid + i * 256; int row = s >> 3; int kcs = (s & 7) ^ (row & 7);
      const ushort* g = A + (size_t)(rowA0 + row) * (size_t)lda + k0 + kcs * 8;
      __builtin_amdgcn_global_load_lds((glb_v*)g, (lds_v*)(&sm[eb + s * 8]), 16, 0, 0);
    }
#pragma unroll
    for (int i = 0; i < 4; ++i) {
      int s = tid + i * 256; int row = s >> 3; int kcs = (s & 7) ^ (row & 7);
      const ushort* g = Bt + (size_t)(col0 + row) * (size_t)ldb + k0 + kcs * 8;
      __builtin_amdgcn_global_load_lds((glb_v*)g, (lds_v*)(&sm[eb + 8192 + s * 8]), 16, 0, 0);
    }
  };

  // precomputed LDS byte offsets (within a buffer) for each fragment
  uint offA[2][4], offB[2][4];
#pragma unroll
  for (int ks = 0; ks < 2; ++ks) {
    int kc = ks * 4 + lsec;
#pragma unroll
    for (int mi = 0; mi < 4; ++mi) {
      int r = wm * 64 + mi * 16 + ln15;
      offA[ks][mi] = (uint)((r * 64 + (kc ^ (r & 7)) * 8) * 2);
    }
#pragma unroll
    for (int ni = 0; ni < 4; ++ni) {
      int c = wn * 64 + ni * 16 + ln15;
      offB[ks][ni] = (uint)(16384 + (c * 64 + (kc ^ (c & 7)) * 8) * 2);
    }
  }

  bf16x8 f0A[4], f0B[4], f1A[4], f1B[4];
  f32x4 acc[4][4] = {};

#define DSR(d, a) asm volatile("ds_read_b128 %0, %1" : "=v"(d) : "v"(a))
#define MMAC(FA, FB) { _Pragma("unroll") for (int mi = 0; mi < 4; ++mi) \
    _Pragma("unroll") for (int ni = 0; ni < 4; ++ni) \
      acc[mi][ni] = __builtin_amdgcn_mfma_f32_16x16x32_bf16(FA[mi], FB[ni], acc[mi][ni], 0, 0, 0); }

  // prologue: tiles 0,1,2 in flight; tile0 landed; slice0(0) reads issued
  stage(0, 0); stage(1, 16384); stage(2, 32768);
  asm volatile("s_waitcnt vmcnt(16)" ::: "memory");   // tile0's 8 landed
  BAR();
  SCH0();
#pragma unroll
  for (int mi = 0; mi < 4; ++mi) DSR(f0A[mi], smb + offA[0][mi]);
#pragma unroll
  for (int ni = 0; ni < 4; ++ni) DSR(f0B[ni], smb + offB[0][ni]);
  SCH0();

  uint bcur = 0;                                      // byte offset of buf(t)
  for (int t = 0; t < NT; ++t) {
    // slice1(t) reads — in flight during MFMA slice0
#pragma unroll
    for (int mi = 0; mi < 4; ++mi) DSR(f1A[mi], smb + bcur + offA[1][mi]);
#pragma unroll
    for (int ni = 0; ni < 4; ++ni) DSR(f1B[ni], smb + bcur + offB[1][ni]);
    SCH0();
    asm volatile("s_waitcnt lgkmcnt(8)" ::: "memory");   // slice0 regs ready
    SCH0();
    PRIO1(); MMAC(f0A, f0B); PRIO0();
    SCH0();
    asm volatile("s_waitcnt lgkmcnt(0)" ::: "memory");   // slice1 regs ready
    BAR();                                               // all waves done with buf(t)
    stage(t + 3, bcur >> 1);                             // refill freed buffer
    SCH0();
    asm volatile("s_waitcnt vmcnt(16)" ::: "memory");    // tile t+1 fully landed
    BAR();
    SCH0();
    const uint bnext = (bcur == 65536u) ? 0u : bcur + 32768u;
#pragma unroll
    for (int mi = 0; mi < 4; ++mi) DSR(f0A[mi], smb + bnext + offA[0][mi]);
#pragma unroll
    for (int ni = 0; ni < 4; ++ni) DSR(f0B[ni], smb + bnext + offB[0][ni]);
    SCH0();
    PRIO1(); MMAC(f1A, f1B); PRIO0();
    SCH0();
    bcur = bnext;
  }
  asm volatile("s_waitcnt vmcnt(0) lgkmcnt(0)" ::: "memory");
#undef DSR
#undef MMAC

  // ---------------- epilogue: C col = lane&15 (+ni*16), row = lsec*4+j (+mi*16)
  if constexpr (QKT) {
#pragma unroll
    for (int mi = 0; mi < 4; ++mi) {
#pragma unroll
      for (int j = 0; j < 4; ++j) {
        const int row = rowA0 + wm * 64 + mi * 16 + lsec * 4 + j;
        float rs = 0.f;
        ushort pb[4];
#pragma unroll
        for (int ni = 0; ni < 4; ++ni) {
          const int col = col0 + wn * 64 + ni * 16 + ln15;
          float p = 0.f;
          if (col <= row) p = __expf(acc[mi][ni][j] * scale);
          pb[ni] = f2bf(p);
          rs += bf2f(pb[ni]);
        }
#pragma unroll
        for (int o = 1; o < 16; o <<= 1) rs += __shfl_xor(rs, o);
        if (ln15 == 0) atomicAdd(&lsum[row], rs);
#pragma unroll
        for (int ni = 0; ni < 4; ++ni) {
          const int col = col0 + wn * 64 + ni * 16 + ln15;
          ((ushort*)outp)[(size_t)row * (size_t)ldc + col] = pb[ni];
        }
      }
    }
  } else {
#pragma unroll
    for (int mi = 0; mi < 4; ++mi) {
#pragma unroll
      for (int j = 0; j < 4; ++j) {
        const int row = rowA0 + wm * 64 + mi * 16 + lsec * 4 + j;
        float inv = 1.f;
        if constexpr (PVM) inv = 1.0f / lsum[row];
#pragma unroll
        for (int ni = 0; ni < 4; ++ni) {
          const int colg = col0 + wn * 64 + ni * 16 + ln15;
          float val = acc[mi][ni][j] * scale;
          if constexpr (PVM) val *= inv;
          if constexpr (HAS_BIAS) val += bias[colg];
          int col = colg; size_t segoff = 0;
          if constexpr (SPLIT3) { int seg = colg >> 10; col = colg & 1023; segoff = (size_t)seg * (size_t)Tn * Cn; }
          if constexpr (OUT_BF16) ((ushort*)outp)[segoff + (size_t)row * (size_t)ldc + col] = f2bf(val);
          else                    ((float*)outp)[segoff + (size_t)row * (size_t)ldc + col] = val;
        }
      }
    }
  }
}

// ---------------------------------------------------------------- transpose (bf16), 64x64 tiles
__global__ __launch_bounds__(256) void transpose64(const ushort* __restrict__ in,
                                                   ushort* __restrict__ out,
                                                   int ldin, int ldout)
{
  __shared__ ushort tile[64][65];
  const int c0 = blockIdx.x * 64, r0 = blockIdx.y * 64;
  const int t = threadIdx.x;
#pragma unroll
  for (int i = t; i < 512; i += 256) {
    int r = i >> 3, kc = i & 7;
    uint4 v = *reinterpret_cast<const uint4*>(in + (size_t)(r0 + r) * ldin + c0 + kc * 8);
    const ushort* u = reinterpret_cast<const ushort*>(&v);
#pragma unroll
    for (int j = 0; j < 8; ++j) tile[r][kc * 8 + j] = u[j];
  }
  __syncthreads();
#pragma unroll
  for (int i = t; i < 512; i += 256) {
    int c = i >> 3, rc = i & 7;
    union { uint4 v; ushort u[8]; } pk;
#pragma unroll
    for (int j = 0; j < 8; ++j) pk.u[j] = tile[rc * 8 + j][c];
    *reinterpret_cast<uint4*>(out + (size_t)(c0 + c) * ldout + r0 + rc * 8) = pk.v;
  }
}

// ---------------------------------------------------------------- launch
extern "C" void kernel_launch(void* const* d_in, const int* in_sizes, int n_in,
                              void* d_out, int out_size, void* d_ws, size_t ws_size,
                              hipStream_t stream)
{
  (void)in_sizes; (void)n_in; (void)out_size; (void)ws_size;
  const float* x  = (const float*)d_in[0];
  const float* Wq = (const float*)d_in[1];
  const float* bq = (const float*)d_in[2];
  const float* Wk = (const float*)d_in[3];
  const float* bk = (const float*)d_in[4];
  const float* Wv = (const float*)d_in[5];
  const float* bv = (const float*)d_in[6];
  const float* Wp = (const float*)d_in[7];
  const float* bp = (const float*)d_in[8];

  char* w = (char*)d_ws;
  const size_t TC = (size_t)Tn * Cn * 2, CC = (size_t)Cn * Cn * 2;
  ushort* xb   = (ushort*)w; w += TC;                    // 16 MB
  ushort* Wqkv = (ushort*)w; w += 3 * CC;                // 6 MB
  ushort* wpb  = (ushort*)w; w += CC;                    // 2 MB
  float*  bqkv = (float*)w;  w += 16384;                 // 12 KB + pad
  float*  lsum = (float*)w;  w += 32768;                 // 32 KB
  ushort* Qb   = (ushort*)w; w += TC;                    // 16 MB
  ushort* Kb   = (ushort*)w; w += TC;                    // 16 MB
  ushort* Vb   = (ushort*)w; w += TC;                    // 16 MB
  ushort* Vt   = (ushort*)w; w += TC;                    // 16 MB
  ushort* Yb   = (ushort*)w; w += TC;                    // 16 MB
  ushort* S    = (ushort*)w; w += (size_t)Tn * Tn * 2;   // 128 MB

  cast_all<<<12292, 256, 0, stream>>>(x, Wq, Wk, Wv, Wp, bq, bk, bv,
                                      xb, Wqkv, wpb, bqkv, lsum);

  // QKV fused: split-3 epilogue -> Qb,Kb,Vb
  gemm_rp<true, true, false, false, true><<<dim3(24, 64), 256, 0, stream>>>(
      xb, Wqkv, bqkv, Qb, nullptr, Cn, Cn, Cn, Cn, 1.0f);

  // V^T for the PV GEMM
  transpose64<<<dim3(Cn / 64, Tn / 64), 256, 0, stream>>>(Vb, Vt, Cn, Tn);

  // P' = exp(Q@K^T/32) (masked) + atomic row-sums l
  // (dispatch-transposed inside the kernel: x sweeps Q rows, y = K panel)
  gemm_rp<true, false, true, false, false><<<dim3(64, 64), 256, 0, stream>>>(
      Qb, Kb, nullptr, S, lsum, Cn, Cn, Cn, Tn, 0.03125f);

  // Y = (P' @ V) / l   (longest-K first, causal K-limit)
  gemm_rp<true, false, false, true, false><<<dim3(8, 64), 256, 0, stream>>>(
      S, Vt, nullptr, Yb, lsum, Tn, Tn, Tn, Cn, 1.0f);

  // out = Y @ Wp^T + bp (fp32 out)
  gemm_rp<false, true, false, false, false><<<dim3(8, 64), 256, 0, stream>>>(
      Yb, wpb, bp, d_out, nullptr, Cn, Cn, Cn, Cn, 1.0f);
}

// Round 9
// 368.019 us; speedup vs baseline: 1.0382x; 1.0382x over previous
//
#include <hip/hip_runtime.h>
#include <hip/hip_bf16.h>

typedef __bf16 bf16x8 __attribute__((ext_vector_type(8)));
typedef float f32x4 __attribute__((ext_vector_type(4)));

static constexpr int Tn = 8192;
static constexpr int Cn = 1024;

#define DEVI __device__ __forceinline__

DEVI float bf2f(ushort u) { union { uint i; float f; } c; c.i = ((uint)u) << 16; return c.f; }
DEVI ushort f2bf(float f) {
  uint x = __builtin_bit_cast(uint, f);
  x += 0x7fffu + ((x >> 16) & 1u);   // RNE
  return (ushort)(x >> 16);
}

typedef const __attribute__((address_space(1))) void glb_v;
typedef __attribute__((address_space(3))) void lds_v;

#define BAR()   __builtin_amdgcn_s_barrier()
#define SCH0()  __builtin_amdgcn_sched_barrier(0)
#define PRIO1() __builtin_amdgcn_s_setprio(1)
#define PRIO0() __builtin_amdgcn_s_setprio(0)

// ---------------------------------------------------------------- cast + concat + l-zero
__global__ __launch_bounds__(256) void cast_all(
    const float* __restrict__ x, const float* __restrict__ wq, const float* __restrict__ wk,
    const float* __restrict__ wv, const float* __restrict__ wp,
    const float* __restrict__ bq, const float* __restrict__ bk, const float* __restrict__ bv,
    ushort* __restrict__ xb, ushort* __restrict__ wqkv, ushort* __restrict__ wpb,
    float* __restrict__ bqkv, float* __restrict__ lsum)
{
  const long long NX = (long long)Tn * Cn;
  const long long NW = (long long)Cn * Cn;      // 2^20
  if (blockIdx.x == 12291) {   // zero the softmax-denominator accumulator
    float4 z; z.x = z.y = z.z = z.w = 0.f;
#pragma unroll
    for (int j = 0; j < 8; ++j) ((float4*)lsum)[threadIdx.x * 8 + j] = z;
    return;
  }
  if (blockIdx.x >= 12288) {   // bias concat (3 blocks)
    int id = ((blockIdx.x - 12288) * 256 + threadIdx.x) * 4;
#pragma unroll
    for (int e = 0; e < 4; ++e) {
      int j = id + e;
      if (j < 3 * Cn) bqkv[j] = j < Cn ? bq[j] : (j < 2 * Cn ? bk[j - Cn] : bv[j - 2 * Cn]);
    }
    return;
  }
  long long i = ((long long)blockIdx.x * 256 + threadIdx.x) * 4;
  const float* src; ushort* dst; long long off;
  if (i < NX) { src = x; dst = xb; off = i; }
  else {
    long long r = i - NX; int seg = (int)(r >> 20); off = r & (NW - 1);
    if (seg < 3) { src = seg == 0 ? wq : seg == 1 ? wk : wv; dst = wqkv + (size_t)seg * NW; }
    else         { src = wp; dst = wpb; }
  }
  float4 v = *reinterpret_cast<const float4*>(src + off);
  ushort4 o; o.x = f2bf(v.x); o.y = f2bf(v.y); o.z = f2bf(v.z); o.w = f2bf(v.w);
  *reinterpret_cast<ushort4*>(dst + off) = o;
}

// ---------------------------------------------------------------- zero 32 MB f32 accumulator
__global__ __launch_bounds__(256) void zero_acc(float4* __restrict__ p)
{
  const int i = (blockIdx.x * 256 + threadIdx.x) * 4;
  float4 z; z.x = z.y = z.z = z.w = 0.f;
#pragma unroll
  for (int j = 0; j < 4; ++j) p[i + j] = z;
}

// ---------------------------------------------------------------- Y = Yacc / lsum -> bf16
__global__ __launch_bounds__(256) void ydiv(const float* __restrict__ Yacc,
                                            const float* __restrict__ lsum,
                                            ushort* __restrict__ Yb)
{
  const int i = (blockIdx.x * 256 + threadIdx.x) * 8;     // 8 elems, same row
  const int row = i >> 10;
  const float inv = 1.0f / lsum[row];
  float4 a = *reinterpret_cast<const float4*>(Yacc + i);
  float4 b = *reinterpret_cast<const float4*>(Yacc + i + 4);
  union { uint4 v; ushort u[8]; } pk;
  pk.u[0] = f2bf(a.x * inv); pk.u[1] = f2bf(a.y * inv);
  pk.u[2] = f2bf(a.z * inv); pk.u[3] = f2bf(a.w * inv);
  pk.u[4] = f2bf(b.x * inv); pk.u[5] = f2bf(b.y * inv);
  pk.u[6] = f2bf(b.z * inv); pk.u[7] = f2bf(b.w * inv);
  *reinterpret_cast<uint4*>(Yb + i) = pk.v;
}

// ---------------------------------------------------------------- register-pipelined GEMM (R6 engine)
// C[M,N] = A[M,K] @ Bt[N,K]^T. 128x128 tile, 4 waves (2x2, per-wave 64x64),
// BK=64, double-buffered 64KB LDS. asm ds_read_b128 pipeline with counted
// lgkmcnt(8)/vmcnt(8); vmcnt never drains to 0 in-loop (rule #18 fences).
// QKT: TRANSPOSED dispatch (blockIdx.x sweeps Q stripes for a fixed K panel ->
//      consecutive blocks share B, the weights-GEMM locality pattern); causal
//      skip; epilogue exp(s/32)+mask -> S bf16 + atomic row-sums lsum.
// PVM: split-K over blockIdx.z (contiguous chunks of the causal K-range);
//      epilogue = f32 atomicAdd into Yacc (no lsum here).
template<bool OUT_BF16, bool HAS_BIAS, bool QKT, bool PVM, bool SPLIT3>
__global__ __launch_bounds__(256, 2)
void gemm_rp(const ushort* __restrict__ A, const ushort* __restrict__ Bt,
             const float* __restrict__ bias, void* __restrict__ outp,
             float* __restrict__ lsum,
             int K, int lda, int ldb, int ldc, float scale)
{
  __shared__ __align__(16) ushort sm[32768];   // 2 bufs x (A 8192 + B 8192) = 64 KB

  const int tid = threadIdx.x, lane = tid & 63, wid = tid >> 6;
  const int wm = wid >> 1, wn = wid & 1;
  const int ln15 = lane & 15, lsec = lane >> 4;

  int bx, by;
  if (QKT) {            // transposed: x sweeps rows (Q), y = shared K panel
    by = blockIdx.x; bx = blockIdx.y;
    if (by < bx) return;
  } else {
    bx = blockIdx.x; by = blockIdx.y;
  }
  const int rowA0 = by * 128, col0 = bx * 128;

  // K-chunk [t0, NT) for this block
  int t0 = 0, NT = K >> 6;
  if (PVM) {
    int ktot = (by + 1) * 2;                   // causal K-tiles for this row
    if (ktot > (K >> 6)) ktot = K >> 6;
    const int nz = (int)gridDim.z, bz = (int)blockIdx.z;
    const int q = ktot / nz, r = ktot % nz;
    const int len = q + (bz < r ? 1 : 0);
    if (len == 0) return;
    t0 = bz < r ? bz * (q + 1) : r * (q + 1) + (bz - r) * q;
    NT = t0 + len;
  }

  const uint smb = (uint)(uintptr_t)&sm[0];

  // staging: 8 x global_load_lds(16B) per tile (clamped to this block's chunk)
  auto stage = [&](int t, int b) {
    const int tt = t < NT ? t : NT - 1;
    const size_t k0 = (size_t)(tt << 6);
#pragma unroll
    for (int i = 0; i < 4; ++i) {
      int s = tid + i * 256; int row = s >> 3; int kcs = (s & 7) ^ (row & 7);
      const ushort* g = A + (size_t)(rowA0 + row) * (size_t)lda + k0 + kcs * 8;
      __builtin_amdgcn_global_load_lds((glb_v*)g, (lds_v*)(&sm[b * 16384 + s * 8]), 16, 0, 0);
    }
#pragma unroll
    for (int i = 0; i < 4; ++i) {
      int s = tid + i * 256; int row = s >> 3; int kcs = (s & 7) ^ (row & 7);
      const ushort* g = Bt + (size_t)(col0 + row) * (size_t)ldb + k0 + kcs * 8;
      __builtin_amdgcn_global_load_lds((glb_v*)g, (lds_v*)(&sm[b * 16384 + 8192 + s * 8]), 16, 0, 0);
    }
  };

  // precomputed LDS byte offsets (within a buffer) for each fragment
  uint offA[2][4], offB[2][4];
#pragma unroll
  for (int ks = 0; ks < 2; ++ks) {
    int kc = ks * 4 + lsec;
#pragma unroll
    for (int mi = 0; mi < 4; ++mi) {
      int r = wm * 64 + mi * 16 + ln15;
      offA[ks][mi] = (uint)((r * 64 + (kc ^ (r & 7)) * 8) * 2);
    }
#pragma unroll
    for (int ni = 0; ni < 4; ++ni) {
      int c = wn * 64 + ni * 16 + ln15;
      offB[ks][ni] = (uint)(16384 + (c * 64 + (kc ^ (c & 7)) * 8) * 2);
    }
  }

  bf16x8 f0A[4], f0B[4], f1A[4], f1B[4];
  f32x4 acc[4][4] = {};

#define DSR(d, a) asm volatile("ds_read_b128 %0, %1" : "=v"(d) : "v"(a))
#define MMAC(FA, FB) { _Pragma("unroll") for (int mi = 0; mi < 4; ++mi) \
    _Pragma("unroll") for (int ni = 0; ni < 4; ++ni) \
      acc[mi][ni] = __builtin_amdgcn_mfma_f32_16x16x32_bf16(FA[mi], FB[ni], acc[mi][ni], 0, 0, 0); }

  // prologue: tiles t0,t0+1 in flight; t0 landed; slice0(t0) reads issued
  stage(t0, 0); stage(t0 + 1, 1);
  asm volatile("s_waitcnt vmcnt(8)" ::: "memory");   // tile t0's 8 landed
  BAR();
  SCH0();
#pragma unroll
  for (int mi = 0; mi < 4; ++mi) DSR(f0A[mi], smb + offA[0][mi]);
#pragma unroll
  for (int ni = 0; ni < 4; ++ni) DSR(f0B[ni], smb + offB[0][ni]);
  SCH0();

  uint boff = 0;
  const int len = NT - t0;
  for (int it = 0; it < len; ++it, boff ^= 32768u) {
    // slice1(t) reads — in flight during MFMA slice0
#pragma unroll
    for (int mi = 0; mi < 4; ++mi) DSR(f1A[mi], smb + boff + offA[1][mi]);
#pragma unroll
    for (int ni = 0; ni < 4; ++ni) DSR(f1B[ni], smb + boff + offB[1][ni]);
    SCH0();
    asm volatile("s_waitcnt lgkmcnt(8)" ::: "memory");   // slice0 regs ready
    SCH0();
    PRIO1(); MMAC(f0A, f0B); PRIO0();
    SCH0();
    asm volatile("s_waitcnt lgkmcnt(0)" ::: "memory");   // slice1 regs ready
    BAR();                                               // all done reading buf b
    stage(t0 + it + 2, it & 1);                          // overwrite buf b
    SCH0();
    asm volatile("s_waitcnt vmcnt(8)" ::: "memory");     // tile t+1 fully landed
    BAR();
    SCH0();
    const uint bo1 = boff ^ 32768u;
#pragma unroll
    for (int mi = 0; mi < 4; ++mi) DSR(f0A[mi], smb + bo1 + offA[0][mi]);
#pragma unroll
    for (int ni = 0; ni < 4; ++ni) DSR(f0B[ni], smb + bo1 + offB[0][ni]);
    SCH0();
    PRIO1(); MMAC(f1A, f1B); PRIO0();
    SCH0();
  }
  asm volatile("s_waitcnt vmcnt(0) lgkmcnt(0)" ::: "memory");
#undef DSR
#undef MMAC

  // ---------------- epilogue: C col = lane&15 (+ni*16), row = lsec*4+j (+mi*16)
  if constexpr (QKT) {
#pragma unroll
    for (int mi = 0; mi < 4; ++mi) {
#pragma unroll
      for (int j = 0; j < 4; ++j) {
        const int row = rowA0 + wm * 64 + mi * 16 + lsec * 4 + j;
        float rs = 0.f;
        ushort pb[4];
#pragma unroll
        for (int ni = 0; ni < 4; ++ni) {
          const int col = col0 + wn * 64 + ni * 16 + ln15;
          float p = 0.f;
          if (col <= row) p = __expf(acc[mi][ni][j] * scale);
          pb[ni] = f2bf(p);
          rs += bf2f(pb[ni]);
        }
#pragma unroll
        for (int o = 1; o < 16; o <<= 1) rs += __shfl_xor(rs, o);
        if (ln15 == 0) atomicAdd(&lsum[row], rs);
#pragma unroll
        for (int ni = 0; ni < 4; ++ni) {
          const int col = col0 + wn * 64 + ni * 16 + ln15;
          ((ushort*)outp)[(size_t)row * (size_t)ldc + col] = pb[ni];
        }
      }
    }
  } else if constexpr (PVM) {
    float* Yacc = (float*)outp;
#pragma unroll
    for (int mi = 0; mi < 4; ++mi) {
#pragma unroll
      for (int j = 0; j < 4; ++j) {
        const int row = rowA0 + wm * 64 + mi * 16 + lsec * 4 + j;
#pragma unroll
        for (int ni = 0; ni < 4; ++ni) {
          const int col = col0 + wn * 64 + ni * 16 + ln15;
          atomicAdd(&Yacc[(size_t)row * (size_t)ldc + col], acc[mi][ni][j]);
        }
      }
    }
  } else {
#pragma unroll
    for (int mi = 0; mi < 4; ++mi) {
#pragma unroll
      for (int j = 0; j < 4; ++j) {
        const int row = rowA0 + wm * 64 + mi * 16 + lsec * 4 + j;
#pragma unroll
        for (int ni = 0; ni < 4; ++ni) {
          const int colg = col0 + wn * 64 + ni * 16 + ln15;
          float val = acc[mi][ni][j] * scale;
          if constexpr (HAS_BIAS) val += bias[colg];
          int col = colg; size_t segoff = 0;
          if constexpr (SPLIT3) { int seg = colg >> 10; col = colg & 1023; segoff = (size_t)seg * (size_t)Tn * Cn; }
          if constexpr (OUT_BF16) ((ushort*)outp)[segoff + (size_t)row * (size_t)ldc + col] = f2bf(val);
          else                    ((float*)outp)[segoff + (size_t)row * (size_t)ldc + col] = val;
        }
      }
    }
  }
}

// ---------------------------------------------------------------- transpose (bf16), 64x64 tiles
__global__ __launch_bounds__(256) void transpose64(const ushort* __restrict__ in,
                                                   ushort* __restrict__ out,
                                                   int ldin, int ldout)
{
  __shared__ ushort tile[64][65];
  const int c0 = blockIdx.x * 64, r0 = blockIdx.y * 64;
  const int t = threadIdx.x;
#pragma unroll
  for (int i = t; i < 512; i += 256) {
    int r = i >> 3, kc = i & 7;
    uint4 v = *reinterpret_cast<const uint4*>(in + (size_t)(r0 + r) * ldin + c0 + kc * 8);
    const ushort* u = reinterpret_cast<const ushort*>(&v);
#pragma unroll
    for (int j = 0; j < 8; ++j) tile[r][kc * 8 + j] = u[j];
  }
  __syncthreads();
#pragma unroll
  for (int i = t; i < 512; i += 256) {
    int c = i >> 3, rc = i & 7;
    union { uint4 v; ushort u[8]; } pk;
#pragma unroll
    for (int j = 0; j < 8; ++j) pk.u[j] = tile[rc * 8 + j][c];
    *reinterpret_cast<uint4*>(out + (size_t)(c0 + c) * ldout + r0 + rc * 8) = pk.v;
  }
}

// ---------------------------------------------------------------- launch
extern "C" void kernel_launch(void* const* d_in, const int* in_sizes, int n_in,
                              void* d_out, int out_size, void* d_ws, size_t ws_size,
                              hipStream_t stream)
{
  (void)in_sizes; (void)n_in; (void)out_size; (void)ws_size;
  const float* x  = (const float*)d_in[0];
  const float* Wq = (const float*)d_in[1];
  const float* bq = (const float*)d_in[2];
  const float* Wk = (const float*)d_in[3];
  const float* bk = (const float*)d_in[4];
  const float* Wv = (const float*)d_in[5];
  const float* bv = (const float*)d_in[6];
  const float* Wp = (const float*)d_in[7];
  const float* bp = (const float*)d_in[8];

  char* w = (char*)d_ws;
  const size_t TC = (size_t)Tn * Cn * 2, CC = (size_t)Cn * Cn * 2;
  ushort* xb   = (ushort*)w; w += TC;                    // 16 MB
  ushort* Wqkv = (ushort*)w; w += 3 * CC;                // 6 MB
  ushort* wpb  = (ushort*)w; w += CC;                    // 2 MB
  float*  bqkv = (float*)w;  w += 16384;                 // 12 KB + pad
  float*  lsum = (float*)w;  w += 32768;                 // 32 KB
  ushort* Qb   = (ushort*)w; w += TC;                    // 16 MB  \ Yacc f32 (32 MB)
  ushort* Kb   = (ushort*)w; w += TC;                    // 16 MB  / aliases Qb+Kb after QKT
  ushort* Vb   = (ushort*)w; w += TC;                    // 16 MB
  ushort* Vt   = (ushort*)w; w += TC;                    // 16 MB
  ushort* Yb   = (ushort*)w; w += TC;                    // 16 MB
  ushort* S    = (ushort*)w; w += (size_t)Tn * Tn * 2;   // 128 MB
  float*  Yacc = (float*)Qb;                             // 8192x1024 f32 = 32 MB

  cast_all<<<12292, 256, 0, stream>>>(x, Wq, Wk, Wv, Wp, bq, bk, bv,
                                      xb, Wqkv, wpb, bqkv, lsum);

  // QKV fused: split-3 epilogue -> Qb,Kb,Vb
  gemm_rp<true, true, false, false, true><<<dim3(24, 64), 256, 0, stream>>>(
      xb, Wqkv, bqkv, Qb, nullptr, Cn, Cn, Cn, Cn, 1.0f);

  // V^T for the PV GEMM
  transpose64<<<dim3(Cn / 64, Tn / 64), 256, 0, stream>>>(Vb, Vt, Cn, Tn);

  // P' = exp(Q@K^T/32) (masked) + atomic row-sums l
  // (transposed dispatch: consecutive blocks share the K panel)
  gemm_rp<true, false, true, false, false><<<dim3(64, 64), 256, 0, stream>>>(
      Qb, Kb, nullptr, S, lsum, Cn, Cn, Cn, Tn, 0.03125f);

  // Yacc = 0 (aliases Qb+Kb, dead after QKT)
  zero_acc<<<2048, 256, 0, stream>>>((float4*)Yacc);

  // Yacc += P' @ V  (split-K=4 over blockIdx.z, f32 atomic accumulation)
  gemm_rp<false, false, false, true, false><<<dim3(8, 64, 4), 256, 0, stream>>>(
      S, Vt, nullptr, Yacc, nullptr, Tn, Tn, Tn, Cn, 1.0f);

  // Yb = bf16(Yacc / l)
  ydiv<<<4096, 256, 0, stream>>>(Yacc, lsum, Yb);

  // out = Y @ Wp^T + bp (fp32 out)
  gemm_rp<false, true, false, false, false><<<dim3(8, 64), 256, 0, stream>>>(
      Yb, wpb, bp, d_out, nullptr, Cn, Cn, Cn, Cn, 1.0f);
}

// Round 10
// 322.223 us; speedup vs baseline: 1.1857x; 1.1421x over previous
//
#include <hip/hip_runtime.h>
#include <hip/hip_bf16.h>

typedef __bf16 bf16x8 __attribute__((ext_vector_type(8)));
typedef float f32x4 __attribute__((ext_vector_type(4)));

static constexpr int Tn = 8192;
static constexpr int Cn = 1024;

#define DEVI __device__ __forceinline__

DEVI float bf2f(ushort u) { union { uint i; float f; } c; c.i = ((uint)u) << 16; return c.f; }
DEVI ushort f2bf(float f) {
  uint x = __builtin_bit_cast(uint, f);
  x += 0x7fffu + ((x >> 16) & 1u);   // RNE
  return (ushort)(x >> 16);
}

typedef const __attribute__((address_space(1))) void glb_v;
typedef __attribute__((address_space(3))) void lds_v;

#define BAR()   __builtin_amdgcn_s_barrier()
#define SCH0()  __builtin_amdgcn_sched_barrier(0)
#define PRIO1() __builtin_amdgcn_s_setprio(1)
#define PRIO0() __builtin_amdgcn_s_setprio(0)

// ---------------------------------------------------------------- cast + concat + l-zero
__global__ __launch_bounds__(256) void cast_all(
    const float* __restrict__ x, const float* __restrict__ wq, const float* __restrict__ wk,
    const float* __restrict__ wv, const float* __restrict__ wp,
    const float* __restrict__ bq, const float* __restrict__ bk, const float* __restrict__ bv,
    ushort* __restrict__ xb, ushort* __restrict__ wqkv, ushort* __restrict__ wpb,
    float* __restrict__ bqkv, float* __restrict__ lsum)
{
  const long long NX = (long long)Tn * Cn;
  const long long NW = (long long)Cn * Cn;      // 2^20
  if (blockIdx.x == 12291) {   // zero the softmax-denominator accumulator
    float4 z; z.x = z.y = z.z = z.w = 0.f;
#pragma unroll
    for (int j = 0; j < 8; ++j) ((float4*)lsum)[threadIdx.x * 8 + j] = z;
    return;
  }
  if (blockIdx.x >= 12288) {   // bias concat (3 blocks)
    int id = ((blockIdx.x - 12288) * 256 + threadIdx.x) * 4;
#pragma unroll
    for (int e = 0; e < 4; ++e) {
      int j = id + e;
      if (j < 3 * Cn) bqkv[j] = j < Cn ? bq[j] : (j < 2 * Cn ? bk[j - Cn] : bv[j - 2 * Cn]);
    }
    return;
  }
  long long i = ((long long)blockIdx.x * 256 + threadIdx.x) * 4;
  const float* src; ushort* dst; long long off;
  if (i < NX) { src = x; dst = xb; off = i; }
  else {
    long long r = i - NX; int seg = (int)(r >> 20); off = r & (NW - 1);
    if (seg < 3) { src = seg == 0 ? wq : seg == 1 ? wk : wv; dst = wqkv + (size_t)seg * NW; }
    else         { src = wp; dst = wpb; }
  }
  float4 v = *reinterpret_cast<const float4*>(src + off);
  ushort4 o; o.x = f2bf(v.x); o.y = f2bf(v.y); o.z = f2bf(v.z); o.w = f2bf(v.w);
  *reinterpret_cast<ushort4*>(dst + off) = o;
}

// ---------------------------------------------------------------- register-pipelined GEMM (R6 engine)
// C[M,N] = A[M,K] @ Bt[N,K]^T. 128x128 tile, 4 waves (2x2, per-wave 64x64),
// BK=64, double-buffered 64KB LDS. asm ds_read_b128 pipeline with counted
// lgkmcnt(8)/vmcnt(8); vmcnt never drains to 0 in-loop (rule #18 fences).
// R10: dispatch-order locality. QKT = COLUMN-MAJOR triangular 1-D grid
// (consecutive blocks share one 256KB K panel -> L2-warm B staging, the
// weights-GEMM pattern). PVM = column-major 1-D (64 consecutive blocks share
// one 2MB Vt panel; S streams; longest rows first within a column).
// QKT epilogue: exp(s/32)+mask -> S bf16 + atomic row-sums lsum.
// PVM epilogue: * 1/lsum[row].
template<bool OUT_BF16, bool HAS_BIAS, bool QKT, bool PVM, bool SPLIT3>
__global__ __launch_bounds__(256, 2)
void gemm_rp(const ushort* __restrict__ A, const ushort* __restrict__ Bt,
             const float* __restrict__ bias, void* __restrict__ outp,
             float* __restrict__ lsum,
             int K, int lda, int ldb, int ldc, float scale)
{
  __shared__ __align__(16) ushort sm[32768];   // 2 bufs x (A 8192 + B 8192) = 64 KB

  const int tid = threadIdx.x, lane = tid & 63, wid = tid >> 6;
  const int wm = wid >> 1, wn = wid & 1;
  const int ln15 = lane & 15, lsec = lane >> 4;

  int bx, by;
  if constexpr (QKT) {
    // column-major triangular decode: column c holds (64-c) blocks, by = c..63
    int id = blockIdx.x, c = 0;
    while (id >= 64 - c) { id -= 64 - c; ++c; }
    bx = c; by = c + id;
  } else if constexpr (PVM) {
    // column-major: 64 consecutive blocks share Vt panel bx; longest rows first
    bx = (int)blockIdx.x >> 6;
    by = 63 - ((int)blockIdx.x & 63);
  } else {
    bx = blockIdx.x; by = blockIdx.y;
  }
  const int rowA0 = by * 128, col0 = bx * 128;
  int NT = K >> 6;
  if constexpr (PVM) { int kl = (by + 1) * 128; if (kl < K) NT = kl >> 6; }

  const uint smb = (uint)(uintptr_t)&sm[0];

  // staging: 8 x global_load_lds(16B) per tile; dst = uniform base + lane*16
  auto stage = [&](int t, int b) {
    const int tt = t < NT ? t : NT - 1;
    const size_t k0 = (size_t)(tt << 6);
#pragma unroll
    for (int i = 0; i < 4; ++i) {
      int s = tid + i * 256; int row = s >> 3; int kcs = (s & 7) ^ (row & 7);
      const ushort* g = A + (size_t)(rowA0 + row) * (size_t)lda + k0 + kcs * 8;
      __builtin_amdgcn_global_load_lds((glb_v*)g, (lds_v*)(&sm[b * 16384 + s * 8]), 16, 0, 0);
    }
#pragma unroll
    for (int i = 0; i < 4; ++i) {
      int s = tid + i * 256; int row = s >> 3; int kcs = (s & 7) ^ (row & 7);
      const ushort* g = Bt + (size_t)(col0 + row) * (size_t)ldb + k0 + kcs * 8;
      __builtin_amdgcn_global_load_lds((glb_v*)g, (lds_v*)(&sm[b * 16384 + 8192 + s * 8]), 16, 0, 0);
    }
  };

  // precomputed LDS byte offsets (within a buffer) for each fragment
  uint offA[2][4], offB[2][4];
#pragma unroll
  for (int ks = 0; ks < 2; ++ks) {
    int kc = ks * 4 + lsec;
#pragma unroll
    for (int mi = 0; mi < 4; ++mi) {
      int r = wm * 64 + mi * 16 + ln15;
      offA[ks][mi] = (uint)((r * 64 + (kc ^ (r & 7)) * 8) * 2);
    }
#pragma unroll
    for (int ni = 0; ni < 4; ++ni) {
      int c = wn * 64 + ni * 16 + ln15;
      offB[ks][ni] = (uint)(16384 + (c * 64 + (kc ^ (c & 7)) * 8) * 2);
    }
  }

  bf16x8 f0A[4], f0B[4], f1A[4], f1B[4];
  f32x4 acc[4][4] = {};

#define DSR(d, a) asm volatile("ds_read_b128 %0, %1" : "=v"(d) : "v"(a))
#define MMAC(FA, FB) { _Pragma("unroll") for (int mi = 0; mi < 4; ++mi) \
    _Pragma("unroll") for (int ni = 0; ni < 4; ++ni) \
      acc[mi][ni] = __builtin_amdgcn_mfma_f32_16x16x32_bf16(FA[mi], FB[ni], acc[mi][ni], 0, 0, 0); }

  // prologue: tiles 0,1 in flight; tile0 landed; slice0(0) reads issued
  stage(0, 0); stage(1, 1);
  asm volatile("s_waitcnt vmcnt(8)" ::: "memory");   // tile0's 8 landed
  BAR();
  SCH0();
#pragma unroll
  for (int mi = 0; mi < 4; ++mi) DSR(f0A[mi], smb + offA[0][mi]);
#pragma unroll
  for (int ni = 0; ni < 4; ++ni) DSR(f0B[ni], smb + offB[0][ni]);
  SCH0();

  uint boff = 0;
  for (int t = 0; t < NT; ++t, boff ^= 32768u) {
    // slice1(t) reads — in flight during MFMA slice0
#pragma unroll
    for (int mi = 0; mi < 4; ++mi) DSR(f1A[mi], smb + boff + offA[1][mi]);
#pragma unroll
    for (int ni = 0; ni < 4; ++ni) DSR(f1B[ni], smb + boff + offB[1][ni]);
    SCH0();
    asm volatile("s_waitcnt lgkmcnt(8)" ::: "memory");   // slice0 regs ready
    SCH0();
    PRIO1(); MMAC(f0A, f0B); PRIO0();
    SCH0();
    asm volatile("s_waitcnt lgkmcnt(0)" ::: "memory");   // slice1 regs ready
    BAR();                                               // all done reading buf b
    stage(t + 2, t & 1);                                 // overwrite buf b
    SCH0();
    asm volatile("s_waitcnt vmcnt(8)" ::: "memory");     // tile t+1 fully landed
    BAR();
    SCH0();
    const uint bo1 = boff ^ 32768u;
#pragma unroll
    for (int mi = 0; mi < 4; ++mi) DSR(f0A[mi], smb + bo1 + offA[0][mi]);
#pragma unroll
    for (int ni = 0; ni < 4; ++ni) DSR(f0B[ni], smb + bo1 + offB[0][ni]);
    SCH0();
    PRIO1(); MMAC(f1A, f1B); PRIO0();
    SCH0();
  }
  asm volatile("s_waitcnt vmcnt(0) lgkmcnt(0)" ::: "memory");
#undef DSR
#undef MMAC

  // ---------------- epilogue: C col = lane&15 (+ni*16), row = lsec*4+j (+mi*16)
  if constexpr (QKT) {
#pragma unroll
    for (int mi = 0; mi < 4; ++mi) {
#pragma unroll
      for (int j = 0; j < 4; ++j) {
        const int row = rowA0 + wm * 64 + mi * 16 + lsec * 4 + j;
        float rs = 0.f;
        ushort pb[4];
#pragma unroll
        for (int ni = 0; ni < 4; ++ni) {
          const int col = col0 + wn * 64 + ni * 16 + ln15;
          float p = 0.f;
          if (col <= row) p = __expf(acc[mi][ni][j] * scale);
          pb[ni] = f2bf(p);
          rs += bf2f(pb[ni]);
        }
#pragma unroll
        for (int o = 1; o < 16; o <<= 1) rs += __shfl_xor(rs, o);
        if (ln15 == 0) atomicAdd(&lsum[row], rs);
#pragma unroll
        for (int ni = 0; ni < 4; ++ni) {
          const int col = col0 + wn * 64 + ni * 16 + ln15;
          ((ushort*)outp)[(size_t)row * (size_t)ldc + col] = pb[ni];
        }
      }
    }
  } else {
#pragma unroll
    for (int mi = 0; mi < 4; ++mi) {
#pragma unroll
      for (int j = 0; j < 4; ++j) {
        const int row = rowA0 + wm * 64 + mi * 16 + lsec * 4 + j;
        float inv = 1.f;
        if constexpr (PVM) inv = 1.0f / lsum[row];
#pragma unroll
        for (int ni = 0; ni < 4; ++ni) {
          const int colg = col0 + wn * 64 + ni * 16 + ln15;
          float val = acc[mi][ni][j] * scale;
          if constexpr (PVM) val *= inv;
          if constexpr (HAS_BIAS) val += bias[colg];
          int col = colg; size_t segoff = 0;
          if constexpr (SPLIT3) { int seg = colg >> 10; col = colg & 1023; segoff = (size_t)seg * (size_t)Tn * Cn; }
          if constexpr (OUT_BF16) ((ushort*)outp)[segoff + (size_t)row * (size_t)ldc + col] = f2bf(val);
          else                    ((float*)outp)[segoff + (size_t)row * (size_t)ldc + col] = val;
        }
      }
    }
  }
}

// ---------------------------------------------------------------- transpose (bf16), 64x64 tiles
__global__ __launch_bounds__(256) void transpose64(const ushort* __restrict__ in,
                                                   ushort* __restrict__ out,
                                                   int ldin, int ldout)
{
  __shared__ ushort tile[64][65];
  const int c0 = blockIdx.x * 64, r0 = blockIdx.y * 64;
  const int t = threadIdx.x;
#pragma unroll
  for (int i = t; i < 512; i += 256) {
    int r = i >> 3, kc = i & 7;
    uint4 v = *reinterpret_cast<const uint4*>(in + (size_t)(r0 + r) * ldin + c0 + kc * 8);
    const ushort* u = reinterpret_cast<const ushort*>(&v);
#pragma unroll
    for (int j = 0; j < 8; ++j) tile[r][kc * 8 + j] = u[j];
  }
  __syncthreads();
#pragma unroll
  for (int i = t; i < 512; i += 256) {
    int c = i >> 3, rc = i & 7;
    union { uint4 v; ushort u[8]; } pk;
#pragma unroll
    for (int j = 0; j < 8; ++j) pk.u[j] = tile[rc * 8 + j][c];
    *reinterpret_cast<uint4*>(out + (size_t)(c0 + c) * ldout + r0 + rc * 8) = pk.v;
  }
}

// ---------------------------------------------------------------- launch
extern "C" void kernel_launch(void* const* d_in, const int* in_sizes, int n_in,
                              void* d_out, int out_size, void* d_ws, size_t ws_size,
                              hipStream_t stream)
{
  (void)in_sizes; (void)n_in; (void)out_size; (void)ws_size;
  const float* x  = (const float*)d_in[0];
  const float* Wq = (const float*)d_in[1];
  const float* bq = (const float*)d_in[2];
  const float* Wk = (const float*)d_in[3];
  const float* bk = (const float*)d_in[4];
  const float* Wv = (const float*)d_in[5];
  const float* bv = (const float*)d_in[6];
  const float* Wp = (const float*)d_in[7];
  const float* bp = (const float*)d_in[8];

  char* w = (char*)d_ws;
  const size_t TC = (size_t)Tn * Cn * 2, CC = (size_t)Cn * Cn * 2;
  ushort* xb   = (ushort*)w; w += TC;                    // 16 MB
  ushort* Wqkv = (ushort*)w; w += 3 * CC;                // 6 MB
  ushort* wpb  = (ushort*)w; w += CC;                    // 2 MB
  float*  bqkv = (float*)w;  w += 16384;                 // 12 KB + pad
  float*  lsum = (float*)w;  w += 32768;                 // 32 KB
  ushort* Qb   = (ushort*)w; w += TC;                    // 16 MB
  ushort* Kb   = (ushort*)w; w += TC;                    // 16 MB
  ushort* Vb   = (ushort*)w; w += TC;                    // 16 MB
  ushort* Vt   = (ushort*)w; w += TC;                    // 16 MB
  ushort* Yb   = (ushort*)w; w += TC;                    // 16 MB
  ushort* S    = (ushort*)w; w += (size_t)Tn * Tn * 2;   // 128 MB

  cast_all<<<12292, 256, 0, stream>>>(x, Wq, Wk, Wv, Wp, bq, bk, bv,
                                      xb, Wqkv, wpb, bqkv, lsum);

  // QKV fused: split-3 epilogue -> Qb,Kb,Vb
  gemm_rp<true, true, false, false, true><<<dim3(24, 64), 256, 0, stream>>>(
      xb, Wqkv, bqkv, Qb, nullptr, Cn, Cn, Cn, Cn, 1.0f);

  // V^T for the PV GEMM
  transpose64<<<dim3(Cn / 64, Tn / 64), 256, 0, stream>>>(Vb, Vt, Cn, Tn);

  // P' = exp(Q@K^T/32) (masked) + atomic row-sums l
  // column-major triangular 1-D grid: consecutive blocks share the K panel
  gemm_rp<true, false, true, false, false><<<dim3(2080), 256, 0, stream>>>(
      Qb, Kb, nullptr, S, lsum, Cn, Cn, Cn, Tn, 0.03125f);

  // Y = (P' @ V) / l  — column-major 1-D: 64 consecutive blocks share a Vt panel
  gemm_rp<true, false, false, true, false><<<dim3(512), 256, 0, stream>>>(
      S, Vt, nullptr, Yb, lsum, Tn, Tn, Tn, Cn, 1.0f);

  // out = Y @ Wp^T + bp (fp32 out)
  gemm_rp<false, true, false, false, false><<<dim3(8, 64), 256, 0, stream>>>(
      Yb, wpb, bp, d_out, nullptr, Cn, Cn, Cn, Cn, 1.0f);
}

// Round 11
// 298.078 us; speedup vs baseline: 1.2818x; 1.0810x over previous
//
#include <hip/hip_runtime.h>
#include <hip/hip_bf16.h>

typedef __bf16 bf16x8 __attribute__((ext_vector_type(8)));
typedef float f32x4 __attribute__((ext_vector_type(4)));

static constexpr int Tn = 8192;
static constexpr int Cn = 1024;

#define DEVI __device__ __forceinline__

DEVI float bf2f(ushort u) { union { uint i; float f; } c; c.i = ((uint)u) << 16; return c.f; }
DEVI ushort f2bf(float f) {
  uint x = __builtin_bit_cast(uint, f);
  x += 0x7fffu + ((x >> 16) & 1u);   // RNE
  return (ushort)(x >> 16);
}

typedef const __attribute__((address_space(1))) void glb_v;
typedef __attribute__((address_space(3))) void lds_v;

#define BAR()   __builtin_amdgcn_s_barrier()
#define SCH0()  __builtin_amdgcn_sched_barrier(0)
#define PRIO1() __builtin_amdgcn_s_setprio(1)
#define PRIO0() __builtin_amdgcn_s_setprio(0)

// ---------------------------------------------------------------- cast + concat + l-zero
__global__ __launch_bounds__(256) void cast_all(
    const float* __restrict__ x, const float* __restrict__ wq, const float* __restrict__ wk,
    const float* __restrict__ wv, const float* __restrict__ wp,
    const float* __restrict__ bq, const float* __restrict__ bk, const float* __restrict__ bv,
    ushort* __restrict__ xb, ushort* __restrict__ wqkv, ushort* __restrict__ wpb,
    float* __restrict__ bqkv, float* __restrict__ lsum)
{
  const long long NX = (long long)Tn * Cn;
  const long long NW = (long long)Cn * Cn;      // 2^20
  if (blockIdx.x == 12291) {   // zero the softmax-denominator accumulator
    float4 z; z.x = z.y = z.z = z.w = 0.f;
#pragma unroll
    for (int j = 0; j < 8; ++j) ((float4*)lsum)[threadIdx.x * 8 + j] = z;
    return;
  }
  if (blockIdx.x >= 12288) {   // bias concat (3 blocks)
    int id = ((blockIdx.x - 12288) * 256 + threadIdx.x) * 4;
#pragma unroll
    for (int e = 0; e < 4; ++e) {
      int j = id + e;
      if (j < 3 * Cn) bqkv[j] = j < Cn ? bq[j] : (j < 2 * Cn ? bk[j - Cn] : bv[j - 2 * Cn]);
    }
    return;
  }
  long long i = ((long long)blockIdx.x * 256 + threadIdx.x) * 4;
  const float* src; ushort* dst; long long off;
  if (i < NX) { src = x; dst = xb; off = i; }
  else {
    long long r = i - NX; int seg = (int)(r >> 20); off = r & (NW - 1);
    if (seg < 3) { src = seg == 0 ? wq : seg == 1 ? wk : wv; dst = wqkv + (size_t)seg * NW; }
    else         { src = wp; dst = wpb; }
  }
  float4 v = *reinterpret_cast<const float4*>(src + off);
  ushort4 o; o.x = f2bf(v.x); o.y = f2bf(v.y); o.z = f2bf(v.z); o.w = f2bf(v.w);
  *reinterpret_cast<ushort4*>(dst + off) = o;
}

// ---------------------------------------------------------------- Y = (P0 + P1) / lsum -> bf16
__global__ __launch_bounds__(256) void ydiv(const ushort* __restrict__ P0,
                                            const ushort* __restrict__ P1,
                                            const float* __restrict__ lsum,
                                            ushort* __restrict__ Yb)
{
  const int i = (blockIdx.x * 256 + threadIdx.x) * 8;     // 8 elems, same row
  const int row = i >> 10;
  const float inv = 1.0f / lsum[row];
  uint4 a = *reinterpret_cast<const uint4*>(P0 + i);
  uint4 b = *reinterpret_cast<const uint4*>(P1 + i);
  const ushort* ua = reinterpret_cast<const ushort*>(&a);
  const ushort* ub = reinterpret_cast<const ushort*>(&b);
  union { uint4 v; ushort u[8]; } pk;
#pragma unroll
  for (int e = 0; e < 8; ++e) pk.u[e] = f2bf((bf2f(ua[e]) + bf2f(ub[e])) * inv);
  *reinterpret_cast<uint4*>(Yb + i) = pk.v;
}

// ---------------------------------------------------------------- register-pipelined GEMM (R6 engine)
// C[M,N] = A[M,K] @ Bt[N,K]^T. 128x128 tile, 4 waves (2x2, per-wave 64x64),
// BK=64, double-buffered 64KB LDS. asm ds_read_b128 pipeline with counted
// lgkmcnt(8)/vmcnt(8); vmcnt never drains to 0 in-loop (rule #18 fences).
// QKT: SUPERTILED triangular dispatch — 8-column groups, row-major inside a
//      group: consecutive blocks share the Q panel, the group's 8 K panels
//      (2MB) stay L2-warm. Epilogue exp(s/32)+mask -> S + atomic row-sums.
// PVM: 1-D grid 1024, split-K=2 (z = id&1): z-chunk = exact half of the causal
//      K-range; bf16 partial stores to outp/outp2 (disjoint, no atomics);
//      longest rows dispatched first (LPT).
template<bool OUT_BF16, bool HAS_BIAS, bool QKT, bool PVM, bool SPLIT3>
__global__ __launch_bounds__(256, 2)
void gemm_rp(const ushort* __restrict__ A, const ushort* __restrict__ Bt,
             const float* __restrict__ bias, void* __restrict__ outp,
             void* __restrict__ outp2, float* __restrict__ lsum,
             int K, int lda, int ldb, int ldc, float scale)
{
  __shared__ __align__(16) ushort sm[32768];   // 2 bufs x (A 8192 + B 8192) = 64 KB

  const int tid = threadIdx.x, lane = tid & 63, wid = tid >> 6;
  const int wm = wid >> 1, wn = wid & 1;
  const int ln15 = lane & 15, lsec = lane >> 4;

  int bx, by, zsel = 0;
  if constexpr (QKT) {
    // supertile decode: column group g (8 cols), row-major within the group
    int id = blockIdx.x, g = 0;
    for (;;) { int sz = 36 + 8 * (56 - 8 * g); if (id < sz || g == 7) break; id -= sz; ++g; }
    int r, c;
    if (id < 36) {           // triangular head of the group (rows 0..7)
      int d = 0;
      while ((d + 1) * (d + 2) / 2 <= id) ++d;
      c = id - d * (d + 1) / 2; r = d;
    } else {                 // full rows (8 cols each)
      int q = id - 36; r = 8 + (q >> 3); c = q & 7;
    }
    by = 8 * g + r; bx = 8 * g + c;
  } else if constexpr (PVM) {
    // 1-D: id -> by=63-(id>>4) (longest first), bx=(id>>1)&7, z=id&1
    by = 63 - ((int)blockIdx.x >> 4);
    bx = ((int)blockIdx.x >> 1) & 7;
    zsel = (int)blockIdx.x & 1;
  } else {
    bx = blockIdx.x; by = blockIdx.y;
  }
  const int rowA0 = by * 128, col0 = bx * 128;

  int t0 = 0, NT = K >> 6;
  if constexpr (PVM) {
    const int half = by + 1;             // causal K-tiles = 2*(by+1); exact halves
    t0 = zsel * half; NT = t0 + half;
  }

  const uint smb = (uint)(uintptr_t)&sm[0];

  // staging: 8 x global_load_lds(16B) per tile; dst = uniform base + lane*16
  auto stage = [&](int t, int b) {
    const int tt = t < NT ? t : NT - 1;
    const size_t k0 = (size_t)(tt << 6);
#pragma unroll
    for (int i = 0; i < 4; ++i) {
      int s = tid + i * 256; int row = s >> 3; int kcs = (s & 7) ^ (row & 7);
      const ushort* g = A + (size_t)(rowA0 + row) * (size_t)lda + k0 + kcs * 8;
      __builtin_amdgcn_global_load_lds((glb_v*)g, (lds_v*)(&sm[b * 16384 + s * 8]), 16, 0, 0);
    }
#pragma unroll
    for (int i = 0; i < 4; ++i) {
      int s = tid + i * 256; int row = s >> 3; int kcs = (s & 7) ^ (row & 7);
      const ushort* g = Bt + (size_t)(col0 + row) * (size_t)ldb + k0 + kcs * 8;
      __builtin_amdgcn_global_load_lds((glb_v*)g, (lds_v*)(&sm[b * 16384 + 8192 + s * 8]), 16, 0, 0);
    }
  };

  // precomputed LDS byte offsets (within a buffer) for each fragment
  uint offA[2][4], offB[2][4];
#pragma unroll
  for (int ks = 0; ks < 2; ++ks) {
    int kc = ks * 4 + lsec;
#pragma unroll
    for (int mi = 0; mi < 4; ++mi) {
      int r = wm * 64 + mi * 16 + ln15;
      offA[ks][mi] = (uint)((r * 64 + (kc ^ (r & 7)) * 8) * 2);
    }
#pragma unroll
    for (int ni = 0; ni < 4; ++ni) {
      int c = wn * 64 + ni * 16 + ln15;
      offB[ks][ni] = (uint)(16384 + (c * 64 + (kc ^ (c & 7)) * 8) * 2);
    }
  }

  bf16x8 f0A[4], f0B[4], f1A[4], f1B[4];
  f32x4 acc[4][4] = {};

#define DSR(d, a) asm volatile("ds_read_b128 %0, %1" : "=v"(d) : "v"(a))
#define MMAC(FA, FB) { _Pragma("unroll") for (int mi = 0; mi < 4; ++mi) \
    _Pragma("unroll") for (int ni = 0; ni < 4; ++ni) \
      acc[mi][ni] = __builtin_amdgcn_mfma_f32_16x16x32_bf16(FA[mi], FB[ni], acc[mi][ni], 0, 0, 0); }

  // prologue: tiles t0,t0+1 in flight; t0 landed; slice0(t0) reads issued
  stage(t0, 0); stage(t0 + 1, 1);
  asm volatile("s_waitcnt vmcnt(8)" ::: "memory");   // tile t0's 8 landed
  BAR();
  SCH0();
#pragma unroll
  for (int mi = 0; mi < 4; ++mi) DSR(f0A[mi], smb + offA[0][mi]);
#pragma unroll
  for (int ni = 0; ni < 4; ++ni) DSR(f0B[ni], smb + offB[0][ni]);
  SCH0();

  uint boff = 0;
  const int len = NT - t0;
  for (int it = 0; it < len; ++it, boff ^= 32768u) {
    // slice1(t) reads — in flight during MFMA slice0
#pragma unroll
    for (int mi = 0; mi < 4; ++mi) DSR(f1A[mi], smb + boff + offA[1][mi]);
#pragma unroll
    for (int ni = 0; ni < 4; ++ni) DSR(f1B[ni], smb + boff + offB[1][ni]);
    SCH0();
    asm volatile("s_waitcnt lgkmcnt(8)" ::: "memory");   // slice0 regs ready
    SCH0();
    PRIO1(); MMAC(f0A, f0B); PRIO0();
    SCH0();
    asm volatile("s_waitcnt lgkmcnt(0)" ::: "memory");   // slice1 regs ready
    BAR();                                               // all done reading buf b
    stage(t0 + it + 2, it & 1);                          // overwrite buf b
    SCH0();
    asm volatile("s_waitcnt vmcnt(8)" ::: "memory");     // tile t+1 fully landed
    BAR();
    SCH0();
    const uint bo1 = boff ^ 32768u;
#pragma unroll
    for (int mi = 0; mi < 4; ++mi) DSR(f0A[mi], smb + bo1 + offA[0][mi]);
#pragma unroll
    for (int ni = 0; ni < 4; ++ni) DSR(f0B[ni], smb + bo1 + offB[0][ni]);
    SCH0();
    PRIO1(); MMAC(f1A, f1B); PRIO0();
    SCH0();
  }
  asm volatile("s_waitcnt vmcnt(0) lgkmcnt(0)" ::: "memory");
#undef DSR
#undef MMAC

  // ---------------- epilogue: C col = lane&15 (+ni*16), row = lsec*4+j (+mi*16)
  if constexpr (QKT) {
#pragma unroll
    for (int mi = 0; mi < 4; ++mi) {
#pragma unroll
      for (int j = 0; j < 4; ++j) {
        const int row = rowA0 + wm * 64 + mi * 16 + lsec * 4 + j;
        float rs = 0.f;
        ushort pb[4];
#pragma unroll
        for (int ni = 0; ni < 4; ++ni) {
          const int col = col0 + wn * 64 + ni * 16 + ln15;
          float p = 0.f;
          if (col <= row) p = __expf(acc[mi][ni][j] * scale);
          pb[ni] = f2bf(p);
          rs += bf2f(pb[ni]);
        }
#pragma unroll
        for (int o = 1; o < 16; o <<= 1) rs += __shfl_xor(rs, o);
        if (ln15 == 0) atomicAdd(&lsum[row], rs);
#pragma unroll
        for (int ni = 0; ni < 4; ++ni) {
          const int col = col0 + wn * 64 + ni * 16 + ln15;
          ((ushort*)outp)[(size_t)row * (size_t)ldc + col] = pb[ni];
        }
      }
    }
  } else if constexpr (PVM) {
    ushort* dst = (ushort*)(zsel ? outp2 : outp);
#pragma unroll
    for (int mi = 0; mi < 4; ++mi) {
#pragma unroll
      for (int j = 0; j < 4; ++j) {
        const int row = rowA0 + wm * 64 + mi * 16 + lsec * 4 + j;
#pragma unroll
        for (int ni = 0; ni < 4; ++ni) {
          const int col = col0 + wn * 64 + ni * 16 + ln15;
          dst[(size_t)row * (size_t)ldc + col] = f2bf(acc[mi][ni][j]);
        }
      }
    }
  } else {
#pragma unroll
    for (int mi = 0; mi < 4; ++mi) {
#pragma unroll
      for (int j = 0; j < 4; ++j) {
        const int row = rowA0 + wm * 64 + mi * 16 + lsec * 4 + j;
#pragma unroll
        for (int ni = 0; ni < 4; ++ni) {
          const int colg = col0 + wn * 64 + ni * 16 + ln15;
          float val = acc[mi][ni][j] * scale;
          if constexpr (HAS_BIAS) val += bias[colg];
          int col = colg; size_t segoff = 0;
          if constexpr (SPLIT3) { int seg = colg >> 10; col = colg & 1023; segoff = (size_t)seg * (size_t)Tn * Cn; }
          if constexpr (OUT_BF16) ((ushort*)outp)[segoff + (size_t)row * (size_t)ldc + col] = f2bf(val);
          else                    ((float*)outp)[segoff + (size_t)row * (size_t)ldc + col] = val;
        }
      }
    }
  }
}

// ---------------------------------------------------------------- transpose (bf16), 64x64 tiles
__global__ __launch_bounds__(256) void transpose64(const ushort* __restrict__ in,
                                                   ushort* __restrict__ out,
                                                   int ldin, int ldout)
{
  __shared__ ushort tile[64][65];
  const int c0 = blockIdx.x * 64, r0 = blockIdx.y * 64;
  const int t = threadIdx.x;
#pragma unroll
  for (int i = t; i < 512; i += 256) {
    int r = i >> 3, kc = i & 7;
    uint4 v = *reinterpret_cast<const uint4*>(in + (size_t)(r0 + r) * ldin + c0 + kc * 8);
    const ushort* u = reinterpret_cast<const ushort*>(&v);
#pragma unroll
    for (int j = 0; j < 8; ++j) tile[r][kc * 8 + j] = u[j];
  }
  __syncthreads();
#pragma unroll
  for (int i = t; i < 512; i += 256) {
    int c = i >> 3, rc = i & 7;
    union { uint4 v; ushort u[8]; } pk;
#pragma unroll
    for (int j = 0; j < 8; ++j) pk.u[j] = tile[rc * 8 + j][c];
    *reinterpret_cast<uint4*>(out + (size_t)(c0 + c) * ldout + r0 + rc * 8) = pk.v;
  }
}

// ---------------------------------------------------------------- launch
extern "C" void kernel_launch(void* const* d_in, const int* in_sizes, int n_in,
                              void* d_out, int out_size, void* d_ws, size_t ws_size,
                              hipStream_t stream)
{
  (void)in_sizes; (void)n_in; (void)out_size; (void)ws_size;
  const float* x  = (const float*)d_in[0];
  const float* Wq = (const float*)d_in[1];
  const float* bq = (const float*)d_in[2];
  const float* Wk = (const float*)d_in[3];
  const float* bk = (const float*)d_in[4];
  const float* Wv = (const float*)d_in[5];
  const float* bv = (const float*)d_in[6];
  const float* Wp = (const float*)d_in[7];
  const float* bp = (const float*)d_in[8];

  char* w = (char*)d_ws;
  const size_t TC = (size_t)Tn * Cn * 2, CC = (size_t)Cn * Cn * 2;
  ushort* xb   = (ushort*)w; w += TC;                    // 16 MB
  ushort* Wqkv = (ushort*)w; w += 3 * CC;                // 6 MB
  ushort* wpb  = (ushort*)w; w += CC;                    // 2 MB
  float*  bqkv = (float*)w;  w += 16384;                 // 12 KB + pad
  float*  lsum = (float*)w;  w += 32768;                 // 32 KB
  ushort* Qb   = (ushort*)w; w += TC;                    // 16 MB  (PV partial0 after QKT)
  ushort* Kb   = (ushort*)w; w += TC;                    // 16 MB
  ushort* Vb   = (ushort*)w; w += TC;                    // 16 MB  (PV partial1 after transpose)
  ushort* Vt   = (ushort*)w; w += TC;                    // 16 MB
  ushort* Yb   = (ushort*)w; w += TC;                    // 16 MB
  ushort* S    = (ushort*)w; w += (size_t)Tn * Tn * 2;   // 128 MB

  cast_all<<<12292, 256, 0, stream>>>(x, Wq, Wk, Wv, Wp, bq, bk, bv,
                                      xb, Wqkv, wpb, bqkv, lsum);

  // QKV fused: split-3 epilogue -> Qb,Kb,Vb
  gemm_rp<true, true, false, false, true><<<dim3(24, 64), 256, 0, stream>>>(
      xb, Wqkv, bqkv, Qb, nullptr, nullptr, Cn, Cn, Cn, Cn, 1.0f);

  // V^T for the PV GEMM
  transpose64<<<dim3(Cn / 64, Tn / 64), 256, 0, stream>>>(Vb, Vt, Cn, Tn);

  // P' = exp(Q@K^T/32) (masked) + atomic row-sums l  (supertiled dispatch)
  gemm_rp<true, false, true, false, false><<<dim3(2080), 256, 0, stream>>>(
      Qb, Kb, nullptr, S, nullptr, lsum, Cn, Cn, Cn, Tn, 0.03125f);

  // PV split-K=2: bf16 partials -> Qb (z=0) / Vb (z=1); longest rows first
  gemm_rp<true, false, false, true, false><<<dim3(1024), 256, 0, stream>>>(
      S, Vt, nullptr, Qb, Vb, nullptr, Tn, Tn, Tn, Cn, 1.0f);

  // Yb = bf16((P0 + P1) / l)
  ydiv<<<4096, 256, 0, stream>>>(Qb, Vb, lsum, Yb);

  // out = Y @ Wp^T + bp (fp32 out)
  gemm_rp<false, true, false, false, false><<<dim3(8, 64), 256, 0, stream>>>(
      Yb, wpb, bp, d_out, nullptr, nullptr, Cn, Cn, Cn, Cn, 1.0f);
}